// Round 10
// baseline (481.611 us; speedup 1.0000x reference)
//
#include <hip/hip_runtime.h>
#include <hip/hip_bf16.h>

#define NN 16384
#define DD 128
#define BK 64          // k floats per pipeline stage
#define NT (NN / BK)   // 256 stages

typedef __attribute__((ext_vector_type(8))) short short8;
typedef __attribute__((ext_vector_type(4))) float f32x4;
typedef __attribute__((ext_vector_type(2))) unsigned u32x2;

__device__ __forceinline__ short f2bf(float f) {
  union { float f; unsigned u; } v; v.f = f;
  unsigned r = v.u + 0x7fffu + ((v.u >> 16) & 1u);   // RNE f32->bf16
  return (short)(r >> 16);
}
__device__ __forceinline__ float bf2f(short s) {
  union { unsigned u; float f; } v; v.u = ((unsigned)(unsigned short)s) << 16;
  return v.f;
}
// f32 (a>=0) -> e4m3 byte of a*4096 (scale folded: bias shift 120-12=108), RNE, FTZ
__device__ __forceinline__ unsigned enc8(float f) {
  unsigned u = __float_as_uint(f);
  u += 0x7FFFFu + ((u >> 20) & 1u);      // RNE into top-3 mantissa bits
  int e8 = (int)(u >> 23) - 108;
  return e8 > 0 ? (unsigned)((e8 << 3) | ((u >> 20) & 7u)) : 0u;
}
// e4m3 byte -> bf16 of a (the /4096 is folded back: +108)
__device__ __forceinline__ short dec8(unsigned b) {
  unsigned E = b >> 3;
  return E ? (short)(((E + 108) << 7) | ((b & 7) << 4)) : (short)0;
}

#define WAITV(n) asm volatile("s_waitcnt vmcnt(" #n ")" ::: "memory")
#define BAR()    do { __builtin_amdgcn_s_barrier(); asm volatile("" ::: "memory"); } while (0)

// ---------------------------------------------------------------------------
// small GEMM: T = In @ W, written in MFMA B-fragment-major layout:
//   element (d, k):  kt=k>>5, dt=d>>4, lane=(d&15)|(((k>>3)&3)<<4), e=k&7
//   Tf[(((kt*8)+dt)*64 + lane)*8 + e]
// ---------------------------------------------------------------------------
template<int IN_BF16>
__global__ __launch_bounds__(256, 1)
void small_gemm(const void* __restrict__ In_, const float* __restrict__ W,
                short* __restrict__ Tf)
{
  __shared__ float sW[DD * DD];   // 64 KB
  const int tid = threadIdx.x;
  {
    const float4* W4 = (const float4*)W;
    float4* sW4 = (float4*)sW;
#pragma unroll
    for (int i = 0; i < 16; ++i) sW4[tid + 256 * i] = W4[tid + 256 * i];
  }
  __syncthreads();

  const int k0 = blockIdx.x * 16;
  const int kk = tid & 15;        // k-row within tile
  const int q  = tid >> 4;        // d-chunk 0..15 -> d = 8q..8q+7
  const long rowoff = (long)(k0 + kk) * DD;

  float acc[8] = {0.f, 0.f, 0.f, 0.f, 0.f, 0.f, 0.f, 0.f};
  if (IN_BF16) {
    const short8* In8 = (const short8*)((const short*)In_ + rowoff);
    for (int j8 = 0; j8 < 16; ++j8) {
      short8 a8 = In8[j8];
#pragma unroll
      for (int c = 0; c < 8; ++c) {
        float a = bf2f(a8[c]);
#pragma unroll
        for (int dd = 0; dd < 8; ++dd)
          acc[dd] += a * sW[(j8 * 8 + c) * DD + q * 8 + dd];
      }
    }
  } else {
    const float4* In4 = (const float4*)((const float*)In_ + rowoff);
    for (int j4 = 0; j4 < 32; ++j4) {
      float4 a4 = In4[j4];
      float av[4] = {a4.x, a4.y, a4.z, a4.w};
#pragma unroll
      for (int c = 0; c < 4; ++c)
#pragma unroll
        for (int dd = 0; dd < 8; ++dd)
          acc[dd] += av[c] * sW[(j4 * 4 + c) * DD + q * 8 + dd];
    }
  }

  const int k    = k0 + kk;
  const int kt   = k >> 5;
  const int ksub = (k >> 3) & 3;
  const int e    = k & 7;
#pragma unroll
  for (int dd = 0; dd < 8; ++dd) {
    const int d  = q * 8 + dd;
    const int dt = d >> 4;
    const int lf = (d & 15) | (ksub << 4);
    Tf[((((long)kt * 8) + dt) * 64 + lf) * 8 + e] = f2bf(acc[dd]);
  }
}

// ---------------------------------------------------------------------------
// agg layer 1: H1 = relu(A @ T0) (bf16 out) + SIDE-PRODUCT: A8 = fp8(A*4096)
// written in A-fragment-major layout A8[((kt*1024 + rt)*64 + lane)*8 + e]
// (per-lane 8B store = 512 B contiguous per wave-instr). Structure = R9.
// ---------------------------------------------------------------------------
__global__ __launch_bounds__(256, 1)
void agg_enc(const float* __restrict__ A, const short* __restrict__ Bf,
             short* __restrict__ H1, char* __restrict__ A8)
{
  __shared__ __align__(16) char sMem[131072];    // A: 4x16KB | B: 4x16KB
  char* sA = sMem;
  char* sB = sMem + 65536;

  const int tid  = threadIdx.x;
  const int lane = tid & 63;
  const int w    = tid >> 6;                     // wave 0..3
  const long rb  = (long)blockIdx.x * 64;        // block row base
  const int arow = lane & 15;
  const int kgrp = lane >> 4;

  int rowi[4], colfi[4];
#pragma unroll
  for (int i = 0; i < 4; ++i) {
    const int o  = w * 4096 + i * 1024 + lane * 16;
    const int rr = o >> 8;
    const int cb = (o & 255) ^ ((rr & 7) << 4);
    rowi[i] = rr;
    colfi[i] = cb >> 2;
  }
  const short* gsrcB = Bf + w * 2048 + lane * 8;
  char* ldsAu = sA + w * 4096;
  char* ldsBu = sB + w * 4096;

  f32x4 acc[8];
#pragma unroll
  for (int dt = 0; dt < 8; ++dt) acc[dt] = (f32x4){0.f, 0.f, 0.f, 0.f};

  auto STAGE = [&](int buf, int t) {
#pragma unroll
    for (int i = 0; i < 4; ++i) {
      const float* g = A + (rb + rowi[i]) * (long)NN + t * BK + colfi[i];
      __builtin_amdgcn_global_load_lds(
          (const __attribute__((address_space(1))) unsigned int*)g,
          (__attribute__((address_space(3))) unsigned int*)(ldsAu + buf * 16384 + i * 1024),
          16, 0, 0x12);
    }
    const short* g = gsrcB + (long)t * 8192;
#pragma unroll
    for (int i = 0; i < 4; ++i)
      __builtin_amdgcn_global_load_lds(
          (const __attribute__((address_space(1))) unsigned int*)(g + i * 512),
          (__attribute__((address_space(3))) unsigned int*)(ldsBu + buf * 16384 + i * 1024),
          16, 0, 0);
  };

  auto COMPUTE = [&](int buf, int t) {
    const char* la = sA + buf * 16384;
    const char* lb = sB + buf * 16384 + lane * 16;
    const int row = w * 16 + arow;
    const int sw  = (arow & 7) << 4;
    const long rtg = (long)blockIdx.x * 4 + w;   // global row-tile of this wave
#pragma unroll
    for (int ks = 0; ks < 2; ++ks) {
      f32x4 a0 = *(const f32x4*)(la + row * 256 + ((ks * 128 + kgrp * 32) ^ sw));
      f32x4 a1 = *(const f32x4*)(la + row * 256 + ((ks * 128 + kgrp * 32 + 16) ^ sw));
      // fp8 side-write (fragment-major, nontemporal)
      u32x2 pk;
      pk[0] = enc8(a0.x) | (enc8(a0.y) << 8) | (enc8(a0.z) << 16) | (enc8(a0.w) << 24);
      pk[1] = enc8(a1.x) | (enc8(a1.y) << 8) | (enc8(a1.z) << 16) | (enc8(a1.w) << 24);
      __builtin_nontemporal_store(pk,
          (u32x2*)(A8 + ((long)(2 * t + ks) * 1024 + rtg) * 512 + lane * 8));
      short8 af;
      af[0] = f2bf(a0.x); af[1] = f2bf(a0.y); af[2] = f2bf(a0.z); af[3] = f2bf(a0.w);
      af[4] = f2bf(a1.x); af[5] = f2bf(a1.y); af[6] = f2bf(a1.z); af[7] = f2bf(a1.w);
#pragma unroll
      for (int dt = 0; dt < 8; ++dt) {
        short8 bf = *(const short8*)(lb + (ks * 8 + dt) * 1024);
        acc[dt] = __builtin_amdgcn_mfma_f32_16x16x32_bf16(af, bf, acc[dt], 0, 0, 0);
      }
    }
  };

  STAGE(0, 0); STAGE(1, 1); STAGE(2, 2);

  int t = 0;
  for (; t < NT - 4; t += 4) {
    WAITV(16); BAR(); STAGE(3, t + 3); COMPUTE(0, t);
    WAITV(16); BAR(); STAGE(0, t + 4); COMPUTE(1, t + 1);
    WAITV(16); BAR(); STAGE(1, t + 5); COMPUTE(2, t + 2);
    WAITV(16); BAR(); STAGE(2, t + 6); COMPUTE(3, t + 3);
  }
  WAITV(16); BAR(); STAGE(3, t + 3); COMPUTE(0, t);
  WAITV(16); BAR(); COMPUTE(1, t + 1);
  WAITV(8);  BAR(); COMPUTE(2, t + 2);
  WAITV(0);  BAR(); COMPUTE(3, t + 3);

#pragma unroll
  for (int dt = 0; dt < 8; ++dt) {
#pragma unroll
    for (int r = 0; r < 4; ++r) {
      float v = acc[dt][r];
      v = v > 0.f ? v : 0.f;
      const long row = rb + w * 16 + kgrp * 4 + r;
      const int  col = dt * 16 + arow;
      __builtin_nontemporal_store(f2bf(v), (short*)H1 + row * DD + col);
    }
  }
}

// ---------------------------------------------------------------------------
// agg layer 2: out = relu(A8 @ T1), A8 fp8 fragment-major (268 MB vs 1074).
// A: 1 gll instr/wave/phase (1 KB contiguous), decoded fp8->bf16 in-reg.
// B: identical to R9. 4-buf, distance 3, counted vmcnt (5 VMEM/phase/wave).
// ---------------------------------------------------------------------------
__global__ __launch_bounds__(256, 1)
void agg_fp8(const char* __restrict__ A8, const short* __restrict__ Bf,
             float* __restrict__ out_)
{
  __shared__ __align__(16) char sMem[81920];     // A: 4x4KB | B: 4x16KB
  char* sA = sMem;
  char* sB = sMem + 16384;

  const int tid  = threadIdx.x;
  const int lane = tid & 63;
  const int w    = tid >> 6;                     // wave 0..3
  const long rb  = (long)blockIdx.x * 64;
  const int arow = lane & 15;
  const int kgrp = lane >> 4;

  const short* gsrcB = Bf + w * 2048 + lane * 8;
  char* ldsAu = sA + w * 1024;
  char* ldsBu = sB + w * 4096;
  const long bb = (long)blockIdx.x * 4 + (w & 1) * 2;  // rt-pair this wave stages

  f32x4 acc[8];
#pragma unroll
  for (int dt = 0; dt < 8; ++dt) acc[dt] = (f32x4){0.f, 0.f, 0.f, 0.f};

  auto STAGE = [&](int buf, int t) {
    // A: chunk (kt = 2t + (w>>1), rows bb..bb+1): 1 KB contiguous
    const char* ga = A8 + ((long)(2 * t + (w >> 1)) * 1024 + bb) * 512 + lane * 16;
    __builtin_amdgcn_global_load_lds(
        (const __attribute__((address_space(1))) unsigned int*)ga,
        (__attribute__((address_space(3))) unsigned int*)(ldsAu + buf * 4096),
        16, 0, 0x12);
    const short* g = gsrcB + (long)t * 8192;
#pragma unroll
    for (int i = 0; i < 4; ++i)
      __builtin_amdgcn_global_load_lds(
          (const __attribute__((address_space(1))) unsigned int*)(g + i * 512),
          (__attribute__((address_space(3))) unsigned int*)(ldsBu + buf * 16384 + i * 1024),
          16, 0, 0);
  };

  auto COMPUTE = [&](int buf) {
    const char* la = sA + buf * 4096 + (w >> 1) * 1024 + (w & 1) * 512 + lane * 8;
    const char* lb = sB + buf * 16384 + lane * 16;
#pragma unroll
    for (int ks = 0; ks < 2; ++ks) {
      u32x2 ab = *(const u32x2*)(la + ks * 2048);
      short8 af;
      af[0] = dec8(ab[0] & 255);         af[1] = dec8((ab[0] >> 8) & 255);
      af[2] = dec8((ab[0] >> 16) & 255); af[3] = dec8(ab[0] >> 24);
      af[4] = dec8(ab[1] & 255);         af[5] = dec8((ab[1] >> 8) & 255);
      af[6] = dec8((ab[1] >> 16) & 255); af[7] = dec8(ab[1] >> 24);
#pragma unroll
      for (int dt = 0; dt < 8; ++dt) {
        short8 bf = *(const short8*)(lb + (ks * 8 + dt) * 1024);
        acc[dt] = __builtin_amdgcn_mfma_f32_16x16x32_bf16(af, bf, acc[dt], 0, 0, 0);
      }
    }
  };

  STAGE(0, 0); STAGE(1, 1); STAGE(2, 2);

  int t = 0;
  for (; t < NT - 4; t += 4) {
    WAITV(10); BAR(); STAGE(3, t + 3); COMPUTE(0);
    WAITV(10); BAR(); STAGE(0, t + 4); COMPUTE(1);
    WAITV(10); BAR(); STAGE(1, t + 5); COMPUTE(2);
    WAITV(10); BAR(); STAGE(2, t + 6); COMPUTE(3);
  }
  WAITV(10); BAR(); STAGE(3, t + 3); COMPUTE(0);
  WAITV(10); BAR(); COMPUTE(1);
  WAITV(5);  BAR(); COMPUTE(2);
  WAITV(0);  BAR(); COMPUTE(3);

  // epilogue: relu + store (fp8 scale fully folded into dec8 — no rescale)
#pragma unroll
  for (int dt = 0; dt < 8; ++dt) {
#pragma unroll
    for (int r = 0; r < 4; ++r) {
      float v = acc[dt][r];
      v = v > 0.f ? v : 0.f;
      const long row = rb + w * 16 + kgrp * 4 + r;
      const int  col = dt * 16 + arow;
      __builtin_nontemporal_store(v, out_ + row * DD + col);
    }
  }
}

// ---------------------------------------------------------------------------
extern "C" void kernel_launch(void* const* d_in, const int* in_sizes, int n_in,
                              void* d_out, int out_size, void* d_ws, size_t ws_size,
                              hipStream_t stream)
{
  const float* A  = (const float*)d_in[0];   // [16384][16384]
  const float* X  = (const float*)d_in[1];   // [16384][128]
  const float* W0 = (const float*)d_in[2];   // [128][128]
  const float* W1 = (const float*)d_in[3];   // [128][128]

  short* Tf = (short*)d_ws;                  // bf16 fragment-major T (4 MB)
  short* H1 = Tf + (size_t)DD * NN;          // bf16 [16384][128] post-relu H1
  char*  A8 = (char*)(H1 + (size_t)NN * DD); // fp8 A, fragment-major (256 MB)

  // layer 0: T0 = X @ W0 ; H1 = relu(A @ T0), A8 = fp8(A) side-write
  small_gemm<0><<<NN / 16, 256, 0, stream>>>(X, W0, Tf);
  agg_enc<<<NN / 64, 256, 0, stream>>>(A, Tf, H1, A8);
  // layer 1: T1 = H1 @ W1 ; out = relu(A8 @ T1)
  small_gemm<1><<<NN / 16, 256, 0, stream>>>(H1, W1, Tf);
  agg_fp8<<<NN / 64, 256, 0, stream>>>(A8, Tf, (float*)d_out);
}